// Round 10
// baseline (110.742 us; speedup 1.0000x reference)
//
#include <hip/hip_runtime.h>
#include <stdint.h>

#define ND       4096           // slice stride (floats) for x / upfold rows
#define NT       16             // O tiles of 64
#define A_OFF    0              // ws: fp16 A[n][o][d]
#define B_OFF    8388608        // ws: fp16 B[n][d][o]
#define N_STRIDE 131072         // bytes per n-slice in each region

typedef float    floatx16 __attribute__((ext_vector_type(16)));
typedef _Float16 half8    __attribute__((ext_vector_type(8)));
typedef _Float16 h2       __attribute__((ext_vector_type(2)));
typedef __fp16   fp16x2   __attribute__((ext_vector_type(2)));

__device__ __forceinline__ uint32_t pkh2(float a, float b) {
    fp16x2 p = __builtin_amdgcn_cvt_pkrtz(a, b);   // v_cvt_pkrtz_f16_f32
    return __builtin_bit_cast(uint32_t, p);
}

__device__ __forceinline__ half8 mk_frag(uint32_t a, uint32_t b, uint32_t c, uint32_t d) {
    union { uint32_t u[4]; half8 v; } U;
    U.u[0] = a; U.u[1] = b; U.u[2] = c; U.u[3] = d;
    return U.v;
}

// sigmoid(s/8) - 0.5 = 0.5*tanh(s/16), odd poly in v=(s/16)^2, packed fp16.
__device__ __forceinline__ uint32_t psig(float s0, float s1) {
    const h2 HI = {(_Float16)41.6f,        (_Float16)41.6f};
    const h2 LO = {(_Float16)-41.6f,       (_Float16)-41.6f};
    const h2 SC = {(_Float16)0.0625f,      (_Float16)0.0625f};
    const h2 C0 = {(_Float16)0.03099238f,  (_Float16)0.03099238f};
    const h2 C1 = {(_Float16)-0.00842090f, (_Float16)-0.00842090f};
    const h2 C2 = {(_Float16)0.00151845f,  (_Float16)0.00151845f};
    const h2 C3 = {(_Float16)-1.02197e-4f, (_Float16)-1.02197e-4f};
    h2 s = __builtin_bit_cast(h2, pkh2(s0, s1));
    s = __builtin_elementwise_min(s, HI);
    s = __builtin_elementwise_max(s, LO);
    h2 ha = s * SC;
    h2 v  = ha * ha;
    h2 w  = C2 + v * C3;
    w     = C1 + v * w;
    w     = C0 + v * w;
    h2 f  = s * w;
    return __builtin_bit_cast(uint32_t, f);
}

__device__ __forceinline__ void gl_lds16(const void* g, void* l) {
    __builtin_amdgcn_global_load_lds(
        (const __attribute__((address_space(1))) unsigned int*)g,
        (__attribute__((address_space(3))) unsigned int*)l, 16, 0, 0);
}

// ---- converter: up (fp32) -> ws fp16 in A[n][o][d] and B[n][d][o] layouts ----
__global__ void __launch_bounds__(256, 4)
conv_kernel(const float* __restrict__ up, uint8_t* __restrict__ ws)
{
    const int tid = threadIdx.x;
    const int n   = blockIdx.x;          // same-n -> same XCD as main kernel
    const int oq  = blockIdx.y;          // 16 groups of 64 o-rows
    const int r8  = tid >> 4;            // 0..15
    const int c   = tid & 15;            // d cols 4c..4c+3
    const float* pr = up + (size_t)(oq * 64 + 2 * r8) * ND + n * 64 + 4 * c;
    uint8_t* An = ws + A_OFF + (size_t)n * N_STRIDE;
    uint8_t* Bn = ws + B_OFF + (size_t)n * N_STRIDE;
    #pragma unroll
    for (int j = 0; j < 2; ++j) {
        float4 fa = *(const float4*)(pr + (size_t)(32 * j) * ND);
        float4 fb = *(const float4*)(pr + (size_t)(32 * j) * ND + ND);
        const int o0 = oq * 64 + 2 * r8 + 32 * j;
        *(uint2*)(An + (size_t)o0 * 128 + 8 * c) =
            make_uint2(pkh2(fa.x, fa.y), pkh2(fa.z, fa.w));
        *(uint2*)(An + (size_t)(o0 + 1) * 128 + 8 * c) =
            make_uint2(pkh2(fb.x, fb.y), pkh2(fb.z, fb.w));
        const float av[4] = {fa.x, fa.y, fa.z, fa.w};
        const float bv[4] = {fb.x, fb.y, fb.z, fb.w};
        #pragma unroll
        for (int k = 0; k < 4; ++k)
            *(uint32_t*)(Bn + (size_t)(4 * c + k) * 2048 + 2 * o0) = pkh2(av[k], bv[k]);
    }
}

__global__ void __launch_bounds__(256, 2)
corr_kernel(const float* __restrict__ x, const uint8_t* __restrict__ ws,
            float* __restrict__ out)
{
    __shared__ __align__(16) uint8_t smem[2][16384];   // [buf][Ub 8192 | Ut 8192]
    __shared__ __align__(16) float Xs[128][68];

    const int tid  = threadIdx.x;
    const int lane = tid & 63;
    const int wid  = tid >> 6;
    const int l31  = lane & 31;
    const int h    = lane >> 5;          // wave half
    const int n    = blockIdx.x;         // XCD swizzle: same n -> same XCD
    const int lb   = blockIdx.y;
    const int lw   = lb * 128 + wid * 32 + l31;

    // gather-staging per-lane constants: LDS[row][pos] holds global d-block pos^(row&7)
    const int ric = lane >> 3;                    // row within 8-row chunk
    const int gsw = (lane & 7) ^ ric;             // global 16B-block this lane fetches
    const uint32_t voffA = ric * 128  + gsw * 16; // within an A chunk (o-rows)
    const uint32_t voffB = ric * 2048 + gsw * 16; // within a B chunk (d-rows)
    const uint8_t* An = ws + A_OFF + (size_t)n * N_STRIDE;
    const uint8_t* Bn = ws + B_OFF + (size_t)n * N_STRIDE;
    const int q0 = 2 * wid, q1 = q0 + 1;          // this wave's two 8-row chunks

    auto stage = [&](int ot, int b) {
        const uint8_t* At = An + ot * 8192;
        const uint8_t* Bt = Bn + ot * 128;
        uint8_t* L = &smem[b][0];
        gl_lds16(At + q0 * 1024  + voffA, L + q0 * 1024);
        gl_lds16(At + q1 * 1024  + voffA, L + q1 * 1024);
        gl_lds16(Bt + q0 * 16384 + voffB, L + 8192 + q0 * 1024);
        gl_lds16(Bt + q1 * 16384 + voffB, L + 8192 + q1 * 1024);
    };

    stage(0, 0);   // fire tile-0 DMA; lands before the X-init barrier

    // ---- phase 0: coalesced X tile (128 rows) -> LDS fp32, build Xf frags ----
    half8 Xf[4];
    {
        const int xr = tid >> 1;
        const int xh = tid & 1;
        const float* xsrc = x + (size_t)(lb * 128 + xr) * ND + n * 64;
        #pragma unroll
        for (int j = 0; j < 8; ++j) {
            const int f4i = xh * 8 + j;
            *(float4*)&Xs[xr][4 * f4i] = *(const float4*)(xsrc + 4 * f4i);
        }
        __syncthreads();   // Xs ready AND all waves' tile-0 DMA drained
        const int rl = wid * 32 + l31;
        #pragma unroll
        for (int kk = 0; kk < 4; ++kk) {
            float4 f1 = *(const float4*)&Xs[rl][16 * kk + 8 * h];
            float4 f2 = *(const float4*)&Xs[rl][16 * kk + 8 * h + 4];
            Xf[kk] = mk_frag(pkh2(f1.x, f1.y), pkh2(f1.z, f1.w),
                             pkh2(f2.x, f2.y), pkh2(f2.z, f2.w));
        }
    }

    floatx16 F0, F1;   // F^T accumulators, d 0..31 / 32..63
    #pragma unroll
    for (int i = 0; i < 16; ++i) { F0[i] = 0.0f; F1[i] = 0.0f; }

    const int sw = l31 & 7;   // swizzle key for reads (same for row and row+32)

    for (int ot = 0; ot < NT; ++ot) {
        const int b = ot & 1;
        if (ot + 1 < NT) stage(ot + 1, b ^ 1);    // fire-and-forget into other buf
        const uint8_t* L = &smem[b][0];

        // GEMM1 A-frags: Ub rows, swizzled b128
        half8 A0k[4], A1k[4];
        #pragma unroll
        for (int kk = 0; kk < 4; ++kk) {
            const int bi = ((2 * kk + h) ^ sw) * 16;
            A0k[kk] = *(const half8*)(L + l31 * 128 + bi);
            A1k[kk] = *(const half8*)(L + (32 + l31) * 128 + bi);
        }
        // GEMM2 A-frags: Ut rows, swizzled b128 (independent of S -> overlap psig)
        half8 B0k[4], B1k[4];
        #pragma unroll
        for (int c2 = 0; c2 < 4; ++c2) {
            const int bi = ((2 * c2 + h) ^ sw) * 16;
            B0k[c2] = *(const half8*)(L + 8192 + l31 * 128 + bi);
            B1k[c2] = *(const half8*)(L + 8192 + (32 + l31) * 128 + bi);
        }

        // ---- GEMM1: S^T = U * X^T ----
        floatx16 S0, S1;
        #pragma unroll
        for (int i = 0; i < 16; ++i) { S0[i] = 0.0f; S1[i] = 0.0f; }
        #pragma unroll
        for (int kk = 0; kk < 4; ++kk) {
            S0 = __builtin_amdgcn_mfma_f32_32x32x16_f16(A0k[kk], Xf[kk], S0, 0, 0, 0);
            S1 = __builtin_amdgcn_mfma_f32_32x32x16_f16(A1k[kk], Xf[kk], S1, 0, 0, 0);
        }

        // ---- sigmoid weights: packed-fp16 odd polynomial ----
        uint32_t P[16];
        #pragma unroll
        for (int m = 0; m < 8; ++m) P[m]     = psig(S0[2*m], S0[2*m+1]);
        #pragma unroll
        for (int m = 0; m < 8; ++m) P[8 + m] = psig(S1[2*m], S1[2*m+1]);

        // ---- GEMM2: F^T += U^T * W — shuffles hoisted ahead of MFMA chain ----
        uint32_t R[8];
        #pragma unroll
        for (int c2 = 0; c2 < 4; ++c2) {
            const uint32_t* Q = P + (c2 >> 1) * 8;
            const int t4 = (c2 & 1) * 4;
            R[2*c2]   = __shfl_xor(h ? Q[t4]     : Q[t4 + 2], 32);
            R[2*c2+1] = __shfl_xor(h ? Q[t4 + 1] : Q[t4 + 3], 32);
        }
        #pragma unroll
        for (int c2 = 0; c2 < 4; ++c2) {
            const uint32_t* Q = P + (c2 >> 1) * 8;
            const int t4 = (c2 & 1) * 4;
            half8 B = h ? mk_frag(R[2*c2], R[2*c2+1], Q[t4 + 2], Q[t4 + 3])
                        : mk_frag(Q[t4], Q[t4 + 1], R[2*c2], R[2*c2+1]);
            F0 = __builtin_amdgcn_mfma_f32_32x32x16_f16(B0k[c2], B, F0, 0, 0, 0);
            F1 = __builtin_amdgcn_mfma_f32_32x32x16_f16(B1k[c2], B, F1, 0, 0, 0);
        }
        __syncthreads();   // drains next-tile DMA + protects buffer swap
    }

    // ---- epilogue: direct store ----
    float* op = out + (size_t)lw * ND + n * 64;
    #pragma unroll
    for (int q = 0; q < 4; ++q) {
        float4 a; a.x = F0[4*q]; a.y = F0[4*q+1]; a.z = F0[4*q+2]; a.w = F0[4*q+3];
        *(float4*)(op + 8*q + 4*h) = a;               // d 0..31
        float4 bq; bq.x = F1[4*q]; bq.y = F1[4*q+1]; bq.z = F1[4*q+2]; bq.w = F1[4*q+3];
        *(float4*)(op + 32 + 8*q + 4*h) = bq;         // d 32..63
    }
}

extern "C" void kernel_launch(void* const* d_in, const int* in_sizes, int n_in,
                              void* d_out, int out_size, void* d_ws, size_t ws_size,
                              hipStream_t stream)
{
    const float* x  = (const float*)d_in[0];
    const float* up = (const float*)d_in[1];
    float* out      = (float*)d_out;
    uint8_t* ws     = (uint8_t*)d_ws;
    conv_kernel<<<dim3(64, 16), dim3(256), 0, stream>>>(up, ws);
    corr_kernel<<<dim3(64, 8),  dim3(256), 0, stream>>>(x, ws, out);
}

// Round 11
// 102.587 us; speedup vs baseline: 1.0795x; 1.0795x over previous
//
#include <hip/hip_runtime.h>
#include <stdint.h>

#define ND   4096               // slice stride (floats) for x / upfold rows
#define NST  8                  // super-tiles of 128 o-rows
#define BUFB 35840              // per-buffer bytes: Ub 18432 + Ut2 17408

typedef float    floatx16 __attribute__((ext_vector_type(16)));
typedef _Float16 half8    __attribute__((ext_vector_type(8)));
typedef _Float16 h2       __attribute__((ext_vector_type(2)));
typedef __fp16   fp16x2   __attribute__((ext_vector_type(2)));

__device__ __forceinline__ uint32_t pkh2(float a, float b) {
    fp16x2 p = __builtin_amdgcn_cvt_pkrtz(a, b);   // v_cvt_pkrtz_f16_f32
    return __builtin_bit_cast(uint32_t, p);
}

__device__ __forceinline__ half8 mk_frag(uint32_t a, uint32_t b, uint32_t c, uint32_t d) {
    union { uint32_t u[4]; half8 v; } U;
    U.u[0] = a; U.u[1] = b; U.u[2] = c; U.u[3] = d;
    return U.v;
}

// sigmoid(s/8) - 0.5 = 0.5*tanh(s/16), odd poly in v=(s/16)^2, packed fp16.
__device__ __forceinline__ uint32_t psig(float s0, float s1) {
    const h2 HI = {(_Float16)41.6f,        (_Float16)41.6f};
    const h2 LO = {(_Float16)-41.6f,       (_Float16)-41.6f};
    const h2 SC = {(_Float16)0.0625f,      (_Float16)0.0625f};
    const h2 C0 = {(_Float16)0.03099238f,  (_Float16)0.03099238f};
    const h2 C1 = {(_Float16)-0.00842090f, (_Float16)-0.00842090f};
    const h2 C2 = {(_Float16)0.00151845f,  (_Float16)0.00151845f};
    const h2 C3 = {(_Float16)-1.02197e-4f, (_Float16)-1.02197e-4f};
    h2 s = __builtin_bit_cast(h2, pkh2(s0, s1));
    s = __builtin_elementwise_min(s, HI);
    s = __builtin_elementwise_max(s, LO);
    h2 ha = s * SC;
    h2 v  = ha * ha;
    h2 w  = C2 + v * C3;
    w     = C1 + v * w;
    w     = C0 + v * w;
    h2 f  = s * w;
    return __builtin_bit_cast(uint32_t, f);
}

__global__ void __launch_bounds__(256, 2)
corr_kernel(const float* __restrict__ x, const float* __restrict__ up,
            float* __restrict__ out)
{
    __shared__ __align__(16) uint8_t smem[2 * BUFB];   // [buf][Ub 18432 | Ut2 17408]

    const int tid  = threadIdx.x;
    const int lane = tid & 63;
    const int wid  = tid >> 6;
    const int l31  = lane & 31;
    const int h    = lane >> 5;          // wave half
    const int r8   = tid >> 4;           // staging row-group (0..15)
    const int c    = tid & 15;           // staging col quad: d = 4c..4c+3
    const int n    = blockIdx.x;         // XCD swizzle: same n -> same XCD
    const int lb   = blockIdx.y;
    const int lw   = lb * 128 + wid * 32 + l31;

    const float* ubase = up + (size_t)n * 64;

    // coalesced super-tile load: rows 2r8+32j (va) / +1 (vb), cols 4c..4c+3
    float4 va[4], vb[4];
    auto load_super = [&](int st) {
        const float* pr = ubase + (size_t)(st * 128 + 2 * r8) * ND + 4 * c;
        #pragma unroll
        for (int j = 0; j < 4; ++j) {
            va[j] = *(const float4*)(pr + (size_t)(32 * j) * ND);
            vb[j] = *(const float4*)(pr + (size_t)(32 * j) * ND + ND);
        }
    };
    // stage regs -> buf b: Ub[128][72] fp16 rows + Ut2[64][68] o-pair rows
    auto stage_super = [&](int b) {
        uint16_t (*Ub)[72]  = (uint16_t (*)[72])(smem + b * BUFB);
        uint32_t (*Ut2)[68] = (uint32_t (*)[68])(smem + b * BUFB + 18432);
        #pragma unroll
        for (int j = 0; j < 4; ++j) {
            *(uint2*)&Ub[2*r8 + 32*j][4*c] =
                make_uint2(pkh2(va[j].x, va[j].y), pkh2(va[j].z, va[j].w));
            *(uint2*)&Ub[2*r8 + 32*j + 1][4*c] =
                make_uint2(pkh2(vb[j].x, vb[j].y), pkh2(vb[j].z, vb[j].w));
            *(uint4*)&Ut2[r8 + 16*j][4*c] =
                make_uint4(pkh2(va[j].x, vb[j].x), pkh2(va[j].y, vb[j].y),
                           pkh2(va[j].z, vb[j].z), pkh2(va[j].w, vb[j].w));
        }
    };

    load_super(0);   // longest-latency path first

    // ---- phase 0: coalesced X tile (128 rows) -> LDS fp32 (overlay), Xf frags ----
    half8 Xf[4];
    {
        float (*Xs)[68] = (float (*)[68])smem;     // 34816 B, overlays buf 0
        const int xr = tid >> 1;
        const int xh = tid & 1;
        const float* xsrc = x + (size_t)(lb * 128 + xr) * ND + n * 64;
        #pragma unroll
        for (int j = 0; j < 8; ++j) {
            const int f4i = xh * 8 + j;
            *(float4*)&Xs[xr][4 * f4i] = *(const float4*)(xsrc + 4 * f4i);
        }
        __syncthreads();
        const int rl = wid * 32 + l31;
        #pragma unroll
        for (int kk = 0; kk < 4; ++kk) {
            float4 f1 = *(const float4*)&Xs[rl][16 * kk + 8 * h];
            float4 f2 = *(const float4*)&Xs[rl][16 * kk + 8 * h + 4];
            Xf[kk] = mk_frag(pkh2(f1.x, f1.y), pkh2(f1.z, f1.w),
                             pkh2(f2.x, f2.y), pkh2(f2.z, f2.w));
        }
        __syncthreads();   // all Xs reads done before buf0 staging overwrites
    }

    stage_super(0);
    load_super(1);
    __syncthreads();

    floatx16 F0, F1;   // F^T accumulators, d 0..31 / 32..63
    #pragma unroll
    for (int i = 0; i < 16; ++i) { F0[i] = 0.0f; F1[i] = 0.0f; }

    for (int st = 0; st < NST; ++st) {
        const int b = st & 1;
        uint16_t (*Ub)[72] = (uint16_t (*)[72])(smem + b * BUFB);
        const uint32_t* utp = (const uint32_t*)(smem + b * BUFB + 18432);

        // hoist sub-tile-0 GEMM1 A-frags into the DS queue ahead of stage writes
        half8 A0k[4], A1k[4];
        #pragma unroll
        for (int kk = 0; kk < 4; ++kk) {
            A0k[kk] = *(const half8*)&Ub[l31][16 * kk + 8 * h];
            A1k[kk] = *(const half8*)&Ub[32 + l31][16 * kk + 8 * h];
        }

        if (st + 1 < NST) stage_super(b ^ 1);   // regs hold super-tile st+1
        if (st + 2 < NST) load_super(st + 2);   // refill into consumed regs

        // ---- two 64-o sub-tiles back-to-back (one barrier for both) ----
        #pragma unroll
        for (int sub = 0; sub < 2; ++sub) {
            if (sub == 1) {   // sub-tile-1 A-frags: Ub rows 64..127
                #pragma unroll
                for (int kk = 0; kk < 4; ++kk) {
                    A0k[kk] = *(const half8*)&Ub[64 + l31][16 * kk + 8 * h];
                    A1k[kk] = *(const half8*)&Ub[96 + l31][16 * kk + 8 * h];
                }
            }
            // GEMM1: S^T = U * X^T
            floatx16 S0, S1;
            #pragma unroll
            for (int i = 0; i < 16; ++i) { S0[i] = 0.0f; S1[i] = 0.0f; }
            #pragma unroll
            for (int kk = 0; kk < 4; ++kk) {
                S0 = __builtin_amdgcn_mfma_f32_32x32x16_f16(A0k[kk], Xf[kk], S0, 0, 0, 0);
                S1 = __builtin_amdgcn_mfma_f32_32x32x16_f16(A1k[kk], Xf[kk], S1, 0, 0, 0);
            }
            // sigmoid weights
            uint32_t P[16];
            #pragma unroll
            for (int m = 0; m < 8; ++m) P[m]     = psig(S0[2*m], S0[2*m+1]);
            #pragma unroll
            for (int m = 0; m < 8; ++m) P[8 + m] = psig(S1[2*m], S1[2*m+1]);
            // GEMM2: F^T += U^T * W, shuffles hoisted
            uint32_t R[8];
            #pragma unroll
            for (int c2 = 0; c2 < 4; ++c2) {
                const uint32_t* Q = P + (c2 >> 1) * 8;
                const int t4 = (c2 & 1) * 4;
                R[2*c2]   = __shfl_xor(h ? Q[t4]     : Q[t4 + 2], 32);
                R[2*c2+1] = __shfl_xor(h ? Q[t4 + 1] : Q[t4 + 3], 32);
            }
            const int obase = 32 * sub;   // o-pair row offset of this sub-tile
            #pragma unroll
            for (int c2 = 0; c2 < 4; ++c2) {
                const uint32_t* Q = P + (c2 >> 1) * 8;
                const int t4 = (c2 & 1) * 4;
                half8 B = h ? mk_frag(R[2*c2], R[2*c2+1], Q[t4 + 2], Q[t4 + 3])
                            : mk_frag(Q[t4], Q[t4 + 1], R[2*c2], R[2*c2+1]);
                const int opb = obase + 8 * c2 + 4 * h;
                uint32_t a0[4], a1[4];
                #pragma unroll
                for (int k = 0; k < 4; ++k) {          // banks 2-way = free
                    a0[k] = utp[(opb + k) * 68 + l31];
                    a1[k] = utp[(opb + k) * 68 + 32 + l31];
                }
                half8 A0 = mk_frag(a0[0], a0[1], a0[2], a0[3]);
                half8 A1 = mk_frag(a1[0], a1[1], a1[2], a1[3]);
                F0 = __builtin_amdgcn_mfma_f32_32x32x16_f16(A0, B, F0, 0, 0, 0);
                F1 = __builtin_amdgcn_mfma_f32_32x32x16_f16(A1, B, F1, 0, 0, 0);
            }
        }
        __syncthreads();   // one barrier per 128-o super-tile
    }

    // ---- epilogue: direct store ----
    float* op = out + (size_t)lw * ND + n * 64;
    #pragma unroll
    for (int q = 0; q < 4; ++q) {
        float4 a; a.x = F0[4*q]; a.y = F0[4*q+1]; a.z = F0[4*q+2]; a.w = F0[4*q+3];
        *(float4*)(op + 8*q + 4*h) = a;               // d 0..31
        float4 bq; bq.x = F1[4*q]; bq.y = F1[4*q+1]; bq.z = F1[4*q+2]; bq.w = F1[4*q+3];
        *(float4*)(op + 32 + 8*q + 4*h) = bq;         // d 32..63
    }
}

extern "C" void kernel_launch(void* const* d_in, const int* in_sizes, int n_in,
                              void* d_out, int out_size, void* d_ws, size_t ws_size,
                              hipStream_t stream)
{
    const float* x  = (const float*)d_in[0];
    const float* up = (const float*)d_in[1];
    float* out      = (float*)d_out;
    corr_kernel<<<dim3(64, 8), dim3(256), 0, stream>>>(x, up, out);
}